// Round 1
// baseline (242.466 us; speedup 1.0000x reference)
//
#include <hip/hip_runtime.h>
#include <math.h>

// Problem constants
#define B_  2
#define L_  512
#define DM_ 256
#define H_  4
#define DK_ 64
#define DV_ 64
#define T_  8
#define PW_ 8

// ---------------------------------------------------------------------------
// GELU (exact, matches jax.nn.gelu(approximate=False))
__device__ __forceinline__ float gelu_exact(float x) {
    return 0.5f * x * (1.0f + erff(x * 0.70710678118654752440f));
}

// phi MLP: params layout per (type,head), stride 97 floats:
//   [0:8)  w0, [8:16) b0, [16:80) W1 (u-major: W1[u*8+w]), [80:88) b1,
//   [88:96) wf, [96] bf
__device__ __forceinline__ float phi_eval(const float* __restrict__ p, float delta) {
    float h1[PW_];
#pragma unroll
    for (int w = 0; w < PW_; ++w)
        h1[w] = gelu_exact(delta * p[w] + p[8 + w]);
    float out = p[96];
#pragma unroll
    for (int u = 0; u < PW_; ++u) {
        float a = p[80 + u];
#pragma unroll
        for (int w = 0; w < PW_; ++w)
            a = fmaf(p[16 + u * 8 + w], h1[w], a);
        out = fmaf(p[88 + u], gelu_exact(a), out);
    }
    return out;
}

// ---------------------------------------------------------------------------
// LayerNorm over DM=256, one block per row (B*L rows), 256 threads
__global__ __launch_bounds__(256) void ln_kernel(const float* __restrict__ q,
                                                 const float* __restrict__ g,
                                                 const float* __restrict__ beta,
                                                 float* __restrict__ qn) {
    __shared__ float red[8];
    const int row = blockIdx.x, tid = threadIdx.x;
    const int lane = tid & 63, wv = tid >> 6;
    float x = q[row * DM_ + tid];
    float s = x;
#pragma unroll
    for (int off = 32; off; off >>= 1) s += __shfl_xor(s, off);
    if (lane == 0) red[wv] = s;
    __syncthreads();
    const float mean = (red[0] + red[1] + red[2] + red[3]) * (1.0f / 256.0f);
    const float d = x - mean;
    float s2 = d * d;
#pragma unroll
    for (int off = 32; off; off >>= 1) s2 += __shfl_xor(s2, off);
    if (lane == 0) red[4 + wv] = s2;
    __syncthreads();
    const float var = (red[4] + red[5] + red[6] + red[7]) * (1.0f / 256.0f);
    qn[row * DM_ + tid] = d * (1.0f / sqrtf(var + 1e-6f)) * g[tid] + beta[tid];
}

// ---------------------------------------------------------------------------
// y[row, n] = sum_k x[row, k] * W[k, n]   (x: rows x 256, W: 256 x 256)
__global__ __launch_bounds__(256) void proj_kernel(const float* __restrict__ x,
                                                   const float* __restrict__ W,
                                                   float* __restrict__ y) {
    __shared__ __align__(16) float xr[DM_];
    const int row = blockIdx.x, tid = threadIdx.x;
    xr[tid] = x[row * DM_ + tid];
    __syncthreads();
    float acc = 0.0f;
#pragma unroll 8
    for (int k = 0; k < DM_; ++k)
        acc = fmaf(xr[k], W[k * DM_ + tid], acc);
    y[row * DM_ + tid] = acc;
}

// out[row, n] = sum_k oh[row, k] * Wo[k, n] + q[row, n]   (residual)
__global__ __launch_bounds__(256) void out_kernel(const float* __restrict__ oh,
                                                  const float* __restrict__ Wo,
                                                  const float* __restrict__ q,
                                                  float* __restrict__ out) {
    __shared__ __align__(16) float xr[DM_];
    const int row = blockIdx.x, tid = threadIdx.x;
    xr[tid] = oh[row * DM_ + tid];
    __syncthreads();
    float acc = 0.0f;
#pragma unroll 8
    for (int k = 0; k < DM_; ++k)
        acc = fmaf(xr[k], Wo[k * DM_ + tid], acc);
    out[row * DM_ + tid] = acc + q[row * DM_ + tid];
}

// ---------------------------------------------------------------------------
// Main attention kernel. One block per (b, i) row, 256 threads, all 4 heads.
__global__ __launch_bounds__(256) void attn_kernel(
        const float* __restrict__ qh, const float* __restrict__ kh,
        const float* __restrict__ vh, const float* __restrict__ t_in,
        const int* __restrict__ c, const float* __restrict__ W0,
        const float* __restrict__ b0, const float* __restrict__ W1,
        const float* __restrict__ b1, const float* __restrict__ Wf,
        const float* __restrict__ bfp, float* __restrict__ oh) {
    __shared__ __align__(16) float prm[T_ * H_ * 97];   // 3104 floats
    __shared__ __align__(16) float qrow[DM_];
    __shared__ float sArr[H_][L_];
    __shared__ float pkArr[H_][L_];
    __shared__ float red[32];
    __shared__ float smax[H_], ssum[H_];

    const int tid = threadIdx.x;
    const int lane = tid & 63, wv = tid >> 6;
    const int row = blockIdx.x;
    const int b = row >> 9;        // / L_
    const int i = row & (L_ - 1);  // % L_

    // stage all phi params into LDS
    for (int x = tid; x < T_ * H_ * 97; x += 256) {
        const int t = x / (H_ * 97);
        const int r = x % (H_ * 97);
        const int h = r / 97;
        const int o = r % 97;
        const int th = t * H_ + h;
        float val;
        if (o < 8)        val = W0[th * 8 + o];
        else if (o < 16)  val = b0[th * 8 + (o - 8)];
        else if (o < 80)  val = W1[th * 64 + (o - 16)];
        else if (o < 88)  val = b1[th * 8 + (o - 80)];
        else if (o < 96)  val = Wf[th * 8 + (o - 88)];
        else              val = bfp[th];
        prm[x] = val;
    }
    qrow[tid] = qh[row * DM_ + tid];
    __syncthreads();

    const float ti = t_in[row];
    const int ci_raw = c[row];
    const bool vi = (ci_raw < T_);
    const int ci = min(max(ci_raw, 0), T_ - 1);

    // ---- pass 1: scores + phiK, per-thread running max -------------------
    float lmax[H_] = {-INFINITY, -INFINITY, -INFINITY, -INFINITY};
    for (int j = tid; j <= i; j += 256) {
        const float tj = t_in[b * L_ + j];
        const int cj_raw = c[b * L_ + j];
        const bool vj = vi && (cj_raw < T_);
        const int cj = min(max(cj_raw, 0), T_ - 1);
        const float delta = ti - tj;
        const float4* kr4 = reinterpret_cast<const float4*>(kh + (size_t)(b * L_ + j) * DM_);
#pragma unroll
        for (int h = 0; h < H_; ++h) {
            const float4* qr4 = reinterpret_cast<const float4*>(&qrow[h * DK_]);
            float dot = 0.0f;
#pragma unroll
            for (int d4 = 0; d4 < DK_ / 4; ++d4) {
                float4 a = qr4[d4];
                float4 kk = kr4[h * (DK_ / 4) + d4];
                dot += a.x * kk.x + a.y * kk.y + a.z * kk.z + a.w * kk.w;
            }
            float pq = 0.0f, pk = 0.0f;
            if (vj) {
                pq = phi_eval(&prm[(ci * H_ + h) * 97], delta);
                pk = phi_eval(&prm[(cj * H_ + h) * 97], delta);
            }
            const float s = dot * pq * pk * 0.125f;  // / sqrt(64)
            sArr[h][j] = s;
            pkArr[h][j] = pk;
            lmax[h] = fmaxf(lmax[h], s);
        }
    }

    // ---- block max per head ----------------------------------------------
#pragma unroll
    for (int h = 0; h < H_; ++h) {
        float m = lmax[h];
#pragma unroll
        for (int off = 32; off; off >>= 1) m = fmaxf(m, __shfl_xor(m, off));
        if (lane == 0) red[wv * H_ + h] = m;
    }
    __syncthreads();
    if (tid < H_) {
        float m = fmaxf(fmaxf(red[0 * H_ + tid], red[1 * H_ + tid]),
                        fmaxf(red[2 * H_ + tid], red[3 * H_ + tid]));
        smax[tid] = m;
    }
    __syncthreads();

    // ---- pass 2a: exponentiate, fold phiK in, partial sums ----------------
    float lsum[H_] = {0.0f, 0.0f, 0.0f, 0.0f};
    for (int j = tid; j <= i; j += 256) {
#pragma unroll
        for (int h = 0; h < H_; ++h) {
            const float e = expf(sArr[h][j] - smax[h]);
            lsum[h] += e;
            sArr[h][j] = e * pkArr[h][j];
        }
    }
#pragma unroll
    for (int h = 0; h < H_; ++h) {
        float s = lsum[h];
#pragma unroll
        for (int off = 32; off; off >>= 1) s += __shfl_xor(s, off);
        if (lane == 0) red[16 + wv * H_ + h] = s;
    }
    __syncthreads();
    if (tid < H_) {
        ssum[tid] = red[16 + 0 * H_ + tid] + red[16 + 1 * H_ + tid] +
                    red[16 + 2 * H_ + tid] + red[16 + 3 * H_ + tid];
    }
    __syncthreads();

    // ---- pass 2b: weighted V accumulation ---------------------------------
    const int h = tid >> 6, d = tid & 63;
    const float inv = 1.0f / ssum[h];
    const float* vbase = vh + (size_t)(b * L_) * DM_ + h * DV_ + d;
    float acc = 0.0f;
#pragma unroll 4
    for (int j = 0; j <= i; ++j)
        acc = fmaf(sArr[h][j], vbase[(size_t)j * DM_], acc);
    oh[row * DM_ + tid] = acc * inv;
}

// ---------------------------------------------------------------------------
extern "C" void kernel_launch(void* const* d_in, const int* in_sizes, int n_in,
                              void* d_out, int out_size, void* d_ws, size_t ws_size,
                              hipStream_t stream) {
    const float* q    = (const float*)d_in[0];
    const float* k    = (const float*)d_in[1];
    const float* v    = (const float*)d_in[2];
    const float* t_in = (const float*)d_in[3];
    const int*   c    = (const int*)d_in[4];
    // d_in[5] = mask: fixed causal triu, never read
    const float* ln_g = (const float*)d_in[6];
    const float* ln_b = (const float*)d_in[7];
    const float* Wq   = (const float*)d_in[8];
    const float* Wk   = (const float*)d_in[9];
    const float* Wv   = (const float*)d_in[10];
    const float* Wo   = (const float*)d_in[11];
    const float* W0   = (const float*)d_in[12];
    const float* b0   = (const float*)d_in[13];
    const float* W1   = (const float*)d_in[14];
    const float* b1   = (const float*)d_in[15];
    const float* Wf   = (const float*)d_in[16];
    const float* bf   = (const float*)d_in[17];
    float* outp = (float*)d_out;

    const size_t NROW = (size_t)B_ * L_;       // 1024
    const size_t SZ   = NROW * DM_;            // 262144 floats per buffer
    float* ws = (float*)d_ws;
    float* qn = ws;            // dies after qh is produced
    float* qh = ws + SZ;
    float* kh = ws + 2 * SZ;
    float* vh = ws + 3 * SZ;
    float* oh = ws;            // reuse qn slot

    ln_kernel<<<dim3(NROW), dim3(256), 0, stream>>>(q, ln_g, ln_b, qn);
    proj_kernel<<<dim3(NROW), dim3(256), 0, stream>>>(qn, Wq, qh);
    proj_kernel<<<dim3(NROW), dim3(256), 0, stream>>>(k, Wk, kh);
    proj_kernel<<<dim3(NROW), dim3(256), 0, stream>>>(v, Wv, vh);
    attn_kernel<<<dim3(NROW), dim3(256), 0, stream>>>(qh, kh, vh, t_in, c,
                                                      W0, b0, W1, b1, Wf, bf, oh);
    out_kernel<<<dim3(NROW), dim3(256), 0, stream>>>(oh, Wo, q, outp);
}

// Round 2
// 209.273 us; speedup vs baseline: 1.1586x; 1.1586x over previous
//
#include <hip/hip_runtime.h>
#include <math.h>

// Problem constants
#define B_  2
#define L_  512
#define DM_ 256
#define H_  4
#define DK_ 64
#define DV_ 64
#define T_  8
#define PW_ 8

// ---------------------------------------------------------------------------
// GELU (exact, matches jax.nn.gelu(approximate=False))
__device__ __forceinline__ float gelu_exact(float x) {
    return 0.5f * x * (1.0f + erff(x * 0.70710678118654752440f));
}

// phi MLP: params layout per type (single head), stride 97 floats:
//   [0:8)  w0, [8:16) b0, [16:80) W1 (u-major: W1[u*8+w]), [80:88) b1,
//   [88:96) wf, [96] bf
__device__ __forceinline__ float phi_eval(const float* __restrict__ p, float delta) {
    float h1[PW_];
#pragma unroll
    for (int w = 0; w < PW_; ++w)
        h1[w] = gelu_exact(delta * p[w] + p[8 + w]);
    float out = p[96];
#pragma unroll
    for (int u = 0; u < PW_; ++u) {
        float a = p[80 + u];
#pragma unroll
        for (int w = 0; w < PW_; ++w)
            a = fmaf(p[16 + u * 8 + w], h1[w], a);
        out = fmaf(p[88 + u], gelu_exact(a), out);
    }
    return out;
}

// ---------------------------------------------------------------------------
// LayerNorm over DM=256, one block per row (B*L rows), 256 threads
__global__ __launch_bounds__(256) void ln_kernel(const float* __restrict__ q,
                                                 const float* __restrict__ g,
                                                 const float* __restrict__ beta,
                                                 float* __restrict__ qn) {
    __shared__ float red[8];
    const int row = blockIdx.x, tid = threadIdx.x;
    const int lane = tid & 63, wv = tid >> 6;
    float x = q[row * DM_ + tid];
    float s = x;
#pragma unroll
    for (int off = 32; off; off >>= 1) s += __shfl_xor(s, off);
    if (lane == 0) red[wv] = s;
    __syncthreads();
    const float mean = (red[0] + red[1] + red[2] + red[3]) * (1.0f / 256.0f);
    const float d = x - mean;
    float s2 = d * d;
#pragma unroll
    for (int off = 32; off; off >>= 1) s2 += __shfl_xor(s2, off);
    if (lane == 0) red[4 + wv] = s2;
    __syncthreads();
    const float var = (red[4] + red[5] + red[6] + red[7]) * (1.0f / 256.0f);
    qn[row * DM_ + tid] = d * (1.0f / sqrtf(var + 1e-6f)) * g[tid] + beta[tid];
}

// ---------------------------------------------------------------------------
// y[row, n] = sum_k x[row, k] * W[k, n], 8 rows per block.
__global__ __launch_bounds__(256) void proj8_kernel(const float* __restrict__ x,
                                                    const float* __restrict__ W,
                                                    float* __restrict__ y) {
    __shared__ __align__(16) float xr[8][DM_];
    const int tid = threadIdx.x;
    const int row0 = blockIdx.x * 8;
    for (int v = tid; v < 8 * DM_; v += 256)
        xr[v >> 8][v & 255] = x[(size_t)(row0 + (v >> 8)) * DM_ + (v & 255)];
    __syncthreads();
    float acc[8] = {0, 0, 0, 0, 0, 0, 0, 0};
#pragma unroll 4
    for (int k = 0; k < DM_; ++k) {
        const float w = W[(size_t)k * DM_ + tid];
#pragma unroll
        for (int r = 0; r < 8; ++r) acc[r] = fmaf(xr[r][k], w, acc[r]);
    }
#pragma unroll
    for (int r = 0; r < 8; ++r)
        y[(size_t)(row0 + r) * DM_ + tid] = acc[r];
}

// out[row, n] = sum_k oh[row, k] * Wo[k, n] + q[row, n], 8 rows per block.
__global__ __launch_bounds__(256) void out8_kernel(const float* __restrict__ oh,
                                                   const float* __restrict__ Wo,
                                                   const float* __restrict__ q,
                                                   float* __restrict__ out) {
    __shared__ __align__(16) float xr[8][DM_];
    const int tid = threadIdx.x;
    const int row0 = blockIdx.x * 8;
    for (int v = tid; v < 8 * DM_; v += 256)
        xr[v >> 8][v & 255] = oh[(size_t)(row0 + (v >> 8)) * DM_ + (v & 255)];
    __syncthreads();
    float acc[8] = {0, 0, 0, 0, 0, 0, 0, 0};
#pragma unroll 4
    for (int k = 0; k < DM_; ++k) {
        const float w = Wo[(size_t)k * DM_ + tid];
#pragma unroll
        for (int r = 0; r < 8; ++r) acc[r] = fmaf(xr[r][k], w, acc[r]);
    }
#pragma unroll
    for (int r = 0; r < 8; ++r)
        out[(size_t)(row0 + r) * DM_ + tid] = acc[r] + q[(size_t)(row0 + r) * DM_ + tid];
}

// ---------------------------------------------------------------------------
// Main attention kernel. One block per (b, row-pair, head): rows i and L-1-i
// sum to constant work -> perfectly balanced grid of B*(L/2)*H = 2048 blocks.
__global__ __launch_bounds__(256) void attn_kernel(
        const float* __restrict__ qh, const float* __restrict__ kh,
        const float* __restrict__ vh, const float* __restrict__ t_in,
        const int* __restrict__ c, const float* __restrict__ W0,
        const float* __restrict__ b0, const float* __restrict__ W1,
        const float* __restrict__ b1, const float* __restrict__ Wf,
        const float* __restrict__ bfp, float* __restrict__ oh) {
    __shared__ __align__(16) float prm[T_ * 97];    // params for this head, all types
    __shared__ float tj_s[L_];
    __shared__ int   cj_s[L_];
    __shared__ __align__(16) float qs[2][DK_];
    __shared__ float sp[2][L_];
    __shared__ float pkA[2][L_];
    __shared__ float red[2][4];
    __shared__ float mrow[2], srow[2];
    __shared__ float pv[4][DV_];

    const int tid = threadIdx.x;
    const int lane = tid & 63, wv = tid >> 6;
    const int idx = blockIdx.x;
    const int h = idx & (H_ - 1);
    const int p = (idx >> 2) & (L_ / 2 - 1);
    const int b = idx >> 10;
    const int i0 = p, i1 = L_ - 1 - p;

    // stage phi params for head h, all 8 types
    for (int x = tid; x < T_ * 97; x += 256) {
        const int t = x / 97;
        const int o = x % 97;
        const int th = t * H_ + h;
        float val;
        if (o < 8)        val = W0[th * 8 + o];
        else if (o < 16)  val = b0[th * 8 + (o - 8)];
        else if (o < 80)  val = W1[th * 64 + (o - 16)];
        else if (o < 88)  val = b1[th * 8 + (o - 80)];
        else if (o < 96)  val = Wf[th * 8 + (o - 88)];
        else              val = bfp[th];
        prm[x] = val;
    }
    // stage timestamps + types for this batch
    for (int j = tid; j < L_; j += 256) {
        tj_s[j] = t_in[b * L_ + j];
        cj_s[j] = c[b * L_ + j];
    }
    // stage the two q rows (head h slice)
    if (tid < 2 * DK_) {
        const int r = tid >> 6, d = tid & 63;
        const int ir = r ? i1 : i0;
        qs[r][d] = qh[(size_t)(b * L_ + ir) * DM_ + h * DK_ + d];
    }
    __syncthreads();

    // ---- pass 1: scores + phiK, per-thread running max -------------------
    float lmax[2] = {-INFINITY, -INFINITY};
#pragma unroll
    for (int r = 0; r < 2; ++r) {
        const int ir = r ? i1 : i0;
        const float ti = tj_s[ir];
        const int ciw = cj_s[ir];
        const bool vi = (ciw < T_);
        const int ci = min(max(ciw, 0), T_ - 1);
        const float* __restrict__ pq_p = &prm[ci * 97];
        const float4* __restrict__ qr4 = reinterpret_cast<const float4*>(qs[r]);
        for (int j = tid; j <= ir; j += 256) {
            const float tj = tj_s[j];
            const int cjw = cj_s[j];
            const bool vj = vi && (cjw < T_);
            const int cj = min(max(cjw, 0), T_ - 1);
            const float delta = ti - tj;
            const float4* __restrict__ kr4 =
                reinterpret_cast<const float4*>(kh + (size_t)(b * L_ + j) * DM_ + h * DK_);
            float dot = 0.0f;
#pragma unroll
            for (int d4 = 0; d4 < DK_ / 4; ++d4) {
                const float4 a = qr4[d4];
                const float4 kk = kr4[d4];
                dot += a.x * kk.x + a.y * kk.y + a.z * kk.z + a.w * kk.w;
            }
            float pq = 0.0f, pk = 0.0f;
            if (vj) {
                pq = phi_eval(pq_p, delta);
                pk = phi_eval(&prm[cj * 97], delta);
            }
            const float s = dot * pq * pk * 0.125f;  // / sqrt(64)
            sp[r][j] = s;
            pkA[r][j] = pk;
            lmax[r] = fmaxf(lmax[r], s);
        }
    }

    // ---- block max per row -------------------------------------------------
#pragma unroll
    for (int r = 0; r < 2; ++r) {
        float m = lmax[r];
#pragma unroll
        for (int off = 32; off; off >>= 1) m = fmaxf(m, __shfl_xor(m, off));
        if (lane == 0) red[r][wv] = m;
    }
    __syncthreads();
    if (tid < 2)
        mrow[tid] = fmaxf(fmaxf(red[tid][0], red[tid][1]),
                          fmaxf(red[tid][2], red[tid][3]));
    __syncthreads();

    // ---- pass 2a: exponentiate, fold phiK in, partial sums ------------------
    float lsum[2] = {0.0f, 0.0f};
#pragma unroll
    for (int r = 0; r < 2; ++r) {
        const int ir = r ? i1 : i0;
        const float m = mrow[r];
        for (int j = tid; j <= ir; j += 256) {
            const float e = __expf(sp[r][j] - m);
            lsum[r] += e;
            sp[r][j] = e * pkA[r][j];
        }
    }
#pragma unroll
    for (int r = 0; r < 2; ++r) {
        float s = lsum[r];
#pragma unroll
        for (int off = 32; off; off >>= 1) s += __shfl_xor(s, off);
        if (lane == 0) red[r][wv] = s;
    }
    __syncthreads();
    if (tid < 2)
        srow[tid] = red[tid][0] + red[tid][1] + red[tid][2] + red[tid][3];
    __syncthreads();

    // ---- pass 2b: weighted V accumulation, 4-way split over j ---------------
    const int g = wv, d = lane;
    const float* __restrict__ vb = vh + (size_t)(b * L_) * DM_ + h * DV_ + d;
#pragma unroll
    for (int r = 0; r < 2; ++r) {
        const int ir = r ? i1 : i0;
        float acc = 0.0f;
        for (int j = g; j <= ir; j += 4)
            acc = fmaf(sp[r][j], vb[(size_t)j * DM_], acc);
        pv[g][d] = acc;
        __syncthreads();
        if (g == 0) {
            const float tot = (pv[0][d] + pv[1][d] + pv[2][d] + pv[3][d]) / srow[r];
            oh[(size_t)(b * L_ + ir) * DM_ + h * DV_ + d] = tot;
        }
        __syncthreads();
    }
}

// ---------------------------------------------------------------------------
extern "C" void kernel_launch(void* const* d_in, const int* in_sizes, int n_in,
                              void* d_out, int out_size, void* d_ws, size_t ws_size,
                              hipStream_t stream) {
    const float* q    = (const float*)d_in[0];
    const float* k    = (const float*)d_in[1];
    const float* v    = (const float*)d_in[2];
    const float* t_in = (const float*)d_in[3];
    const int*   c    = (const int*)d_in[4];
    // d_in[5] = mask: fixed causal triu, never read
    const float* ln_g = (const float*)d_in[6];
    const float* ln_b = (const float*)d_in[7];
    const float* Wq   = (const float*)d_in[8];
    const float* Wk   = (const float*)d_in[9];
    const float* Wv   = (const float*)d_in[10];
    const float* Wo   = (const float*)d_in[11];
    const float* W0   = (const float*)d_in[12];
    const float* b0   = (const float*)d_in[13];
    const float* W1   = (const float*)d_in[14];
    const float* b1   = (const float*)d_in[15];
    const float* Wf   = (const float*)d_in[16];
    const float* bf   = (const float*)d_in[17];
    float* outp = (float*)d_out;

    const size_t NROW = (size_t)B_ * L_;       // 1024
    const size_t SZ   = NROW * DM_;            // 262144 floats per buffer
    float* ws = (float*)d_ws;
    float* qn = ws;            // dies after qh is produced
    float* qh = ws + SZ;
    float* kh = ws + 2 * SZ;
    float* vh = ws + 3 * SZ;
    float* oh = ws;            // reuse qn slot

    ln_kernel<<<dim3(NROW), dim3(256), 0, stream>>>(q, ln_g, ln_b, qn);
    proj8_kernel<<<dim3(NROW / 8), dim3(256), 0, stream>>>(qn, Wq, qh);
    proj8_kernel<<<dim3(NROW / 8), dim3(256), 0, stream>>>(k, Wk, kh);
    proj8_kernel<<<dim3(NROW / 8), dim3(256), 0, stream>>>(v, Wv, vh);
    attn_kernel<<<dim3((size_t)B_ * (L_ / 2) * H_), dim3(256), 0, stream>>>(
        qh, kh, vh, t_in, c, W0, b0, W1, b1, Wf, bf, oh);
    out8_kernel<<<dim3(NROW / 8), dim3(256), 0, stream>>>(oh, Wo, q, outp);
}

// Round 3
// 154.279 us; speedup vs baseline: 1.5716x; 1.3565x over previous
//
#include <hip/hip_runtime.h>
#include <math.h>

// Problem constants
#define B_  2
#define L_  512
#define DM_ 256
#define H_  4
#define DK_ 64
#define DV_ 64
#define T_  8
#define PW_ 8

// ---------------------------------------------------------------------------
// Fast exact-GELU: erf via Abramowitz-Stegun 7.1.26 (|err| <= 1.5e-7), branch-free.
__device__ __forceinline__ float gelu_fast(float x) {
    const float z  = x * 0.70710678118654752440f;
    const float az = fabsf(z);
    const float t  = __builtin_amdgcn_rcpf(fmaf(0.3275911f, az, 1.0f));
    float p = fmaf(t, 1.061405429f, -1.453152027f);
    p = fmaf(t, p, 1.421413741f);
    p = fmaf(t, p, -0.284496736f);
    p = fmaf(t, p, 0.254829592f);
    p *= t;
    const float e  = __expf(-az * az);
    float er = fmaf(-p, e, 1.0f);          // erf(|z|)
    er = copysignf(er, z);
    return 0.5f * x * (1.0f + er);
}

// phi MLP with wave-uniform type: 33 scalar params in registers, W1 via
// uniform-address (broadcast) LDS float4 reads.
__device__ __forceinline__ float phi_eval_u(
        const float* __restrict__ w0r, const float* __restrict__ b0r,
        const float4* __restrict__ W14, const float* __restrict__ b1r,
        const float* __restrict__ wfr, float bfv, float delta) {
    float h1[PW_];
#pragma unroll
    for (int w = 0; w < PW_; ++w)
        h1[w] = gelu_fast(fmaf(delta, w0r[w], b0r[w]));
    float out = bfv;
#pragma unroll
    for (int u = 0; u < PW_; ++u) {
        const float4 c0 = W14[u * 2];
        const float4 c1 = W14[u * 2 + 1];
        float a = b1r[u];
        a = fmaf(c0.x, h1[0], a); a = fmaf(c0.y, h1[1], a);
        a = fmaf(c0.z, h1[2], a); a = fmaf(c0.w, h1[3], a);
        a = fmaf(c1.x, h1[4], a); a = fmaf(c1.y, h1[5], a);
        a = fmaf(c1.z, h1[6], a); a = fmaf(c1.w, h1[7], a);
        out = fmaf(wfr[u], gelu_fast(a), out);
    }
    return out;
}

// ---------------------------------------------------------------------------
// Fused LN + 3 projections. seg 0: qh = LN(q)@Wq ; seg 1: kh = k@Wk ; seg 2: vh = v@Wv.
__global__ __launch_bounds__(256) void qkv_kernel(
        const float* __restrict__ q, const float* __restrict__ k,
        const float* __restrict__ v, const float* __restrict__ ln_g,
        const float* __restrict__ ln_b, const float* __restrict__ Wq,
        const float* __restrict__ Wk, const float* __restrict__ Wv,
        float* __restrict__ qh, float* __restrict__ kh, float* __restrict__ vh) {
    __shared__ __align__(16) float xr[8][DM_];
    const int tid = threadIdx.x;
    const int seg = blockIdx.x >> 7;
    const int row0 = (blockIdx.x & 127) * 8;
    const float* src = seg == 0 ? q : (seg == 1 ? k : v);
    const float* W   = seg == 0 ? Wq : (seg == 1 ? Wk : Wv);
    float* dst       = seg == 0 ? qh : (seg == 1 ? kh : vh);
    for (int x = tid; x < 8 * DM_; x += 256)
        xr[x >> 8][x & 255] = src[(size_t)row0 * DM_ + x];
    __syncthreads();
    if (seg == 0) {   // LayerNorm the 8 staged rows (4 waves x 2 rows)
        const int lane = tid & 63, wv = tid >> 6;
#pragma unroll
        for (int rr = 0; rr < 2; ++rr) {
            const int r = wv * 2 + rr;
            float x0 = xr[r][lane], x1 = xr[r][lane + 64];
            float x2 = xr[r][lane + 128], x3 = xr[r][lane + 192];
            float s = x0 + x1 + x2 + x3;
#pragma unroll
            for (int off = 32; off; off >>= 1) s += __shfl_xor(s, off);
            const float mean = s * (1.0f / 256.0f);
            x0 -= mean; x1 -= mean; x2 -= mean; x3 -= mean;
            float s2 = x0 * x0 + x1 * x1 + x2 * x2 + x3 * x3;
#pragma unroll
            for (int off = 32; off; off >>= 1) s2 += __shfl_xor(s2, off);
            const float rstd = rsqrtf(s2 * (1.0f / 256.0f) + 1e-6f);
            xr[r][lane]       = x0 * rstd * ln_g[lane]       + ln_b[lane];
            xr[r][lane + 64]  = x1 * rstd * ln_g[lane + 64]  + ln_b[lane + 64];
            xr[r][lane + 128] = x2 * rstd * ln_g[lane + 128] + ln_b[lane + 128];
            xr[r][lane + 192] = x3 * rstd * ln_g[lane + 192] + ln_b[lane + 192];
        }
        __syncthreads();
    }
    float acc[8] = {0, 0, 0, 0, 0, 0, 0, 0};
#pragma unroll 4
    for (int kk = 0; kk < DM_; ++kk) {
        const float w = W[(size_t)kk * DM_ + tid];
#pragma unroll
        for (int r = 0; r < 8; ++r) acc[r] = fmaf(xr[r][kk], w, acc[r]);
    }
#pragma unroll
    for (int r = 0; r < 8; ++r)
        dst[(size_t)(row0 + r) * DM_ + tid] = acc[r];
}

// ---------------------------------------------------------------------------
// phiK table: pkT[b][h][i][j] = phi_{c_j,h}(t_i - t_j) * (c_j < T).
// One block per (b, column-pair, h): type is block-uniform -> params in regs.
__global__ __launch_bounds__(256) void phik_kernel(
        const float* __restrict__ t_in, const int* __restrict__ c,
        const float* __restrict__ W0, const float* __restrict__ b0,
        const float* __restrict__ W1, const float* __restrict__ b1,
        const float* __restrict__ Wf, const float* __restrict__ bfp,
        float* __restrict__ pkT) {
    __shared__ float ts[L_];
    __shared__ __align__(16) float W1s[T_ * 64];
    const int tid = threadIdx.x;
    const int idx = blockIdx.x;
    const int h = idx & (H_ - 1);
    const int p = (idx >> 2) & (L_ / 2 - 1);
    const int b = idx >> 10;
    for (int x = tid; x < L_; x += 256) ts[x] = t_in[b * L_ + x];
    for (int x = tid; x < T_ * 64; x += 256)
        W1s[x] = W1[((x >> 6) * H_ + h) * 64 + (x & 63)];
    __syncthreads();
#pragma unroll
    for (int ph = 0; ph < 2; ++ph) {
        const int jc = ph ? (L_ - 1 - p) : p;
        const int cw = c[b * L_ + jc];
        const bool vj = (cw < T_);
        const int ct = min(max(cw, 0), T_ - 1);
        const int base = ct * H_ + h;
        float w0r[8], b0r[8], b1r[8], wfr[8];
#pragma unroll
        for (int w = 0; w < 8; ++w) {
            w0r[w] = W0[base * 8 + w];
            b0r[w] = b0[base * 8 + w];
            b1r[w] = b1[base * 8 + w];
            wfr[w] = Wf[base * 8 + w];
        }
        const float bfv = bfp[base];
        const float4* W14 = reinterpret_cast<const float4*>(&W1s[ct * 64]);
        const float tj = ts[jc];
        float* dst = pkT + ((size_t)(b * H_ + h) * L_) * L_ + jc;
        for (int i = jc + tid; i < L_; i += 256) {
            const float val = vj ? phi_eval_u(w0r, b0r, W14, b1r, wfr, bfv, ts[i] - tj)
                                 : 0.0f;
            dst[(size_t)i * L_] = val;
        }
    }
}

// ---------------------------------------------------------------------------
// Attention: one block per (b, row-pair, h). phiQ inline (type uniform per row),
// phiK from table. Two sequential row-phases share LDS buffers.
__global__ __launch_bounds__(256) void attn_kernel(
        const float* __restrict__ qh, const float* __restrict__ kh,
        const float* __restrict__ vh, const float* __restrict__ t_in,
        const int* __restrict__ c, const float* __restrict__ W0,
        const float* __restrict__ b0, const float* __restrict__ W1,
        const float* __restrict__ b1, const float* __restrict__ Wf,
        const float* __restrict__ bfp, const float* __restrict__ pkT,
        float* __restrict__ oh) {
    __shared__ float ts[L_];
    __shared__ __align__(16) float W1s[T_ * 64];
    __shared__ __align__(16) float qs[DK_];
    __shared__ float sp[L_], pkA[L_];
    __shared__ float redm[4], reds[4];
    __shared__ float pv[4][DV_];

    const int tid = threadIdx.x, lane = tid & 63, wv = tid >> 6;
    const int idx = blockIdx.x;
    const int h = idx & (H_ - 1);
    const int p = (idx >> 2) & (L_ / 2 - 1);
    const int b = idx >> 10;

    for (int x = tid; x < L_; x += 256) ts[x] = t_in[b * L_ + x];
    for (int x = tid; x < T_ * 64; x += 256)
        W1s[x] = W1[((x >> 6) * H_ + h) * 64 + (x & 63)];
    __syncthreads();

#pragma unroll
    for (int ph = 0; ph < 2; ++ph) {
        const int i = ph ? (L_ - 1 - p) : p;
        const int cw = c[b * L_ + i];
        const bool vi = (cw < T_);
        const int ct = min(max(cw, 0), T_ - 1);
        const int base = ct * H_ + h;
        float w0r[8], b0r[8], b1r[8], wfr[8];
#pragma unroll
        for (int w = 0; w < 8; ++w) {
            w0r[w] = W0[base * 8 + w];
            b0r[w] = b0[base * 8 + w];
            b1r[w] = b1[base * 8 + w];
            wfr[w] = Wf[base * 8 + w];
        }
        const float bfv = bfp[base];
        const float4* W14 = reinterpret_cast<const float4*>(&W1s[ct * 64]);
        if (tid < DK_)
            qs[tid] = qh[(size_t)(b * L_ + i) * DM_ + h * DK_ + tid];
        __syncthreads();

        const float ti = ts[i];
        const float4* qs4 = reinterpret_cast<const float4*>(qs);
        const float* pkrow = pkT + ((size_t)(b * H_ + h) * L_ + i) * L_;

        // pass 1: scores (dot * phiQ * phiK / 8), phiK from table
        float lmax = -INFINITY;
        for (int j = tid; j <= i; j += 256) {
            const float pk = pkrow[j];
            const float pq = vi ? phi_eval_u(w0r, b0r, W14, b1r, wfr, bfv, ti - ts[j])
                                : 0.0f;
            const float4* kr4 =
                reinterpret_cast<const float4*>(kh + (size_t)(b * L_ + j) * DM_ + h * DK_);
            float dot = 0.0f;
#pragma unroll
            for (int d4 = 0; d4 < DK_ / 4; ++d4) {
                const float4 a = qs4[d4];
                const float4 kk = kr4[d4];
                dot = fmaf(a.x, kk.x, fmaf(a.y, kk.y, fmaf(a.z, kk.z, fmaf(a.w, kk.w, dot))));
            }
            const float s = dot * pq * pk * 0.125f;
            sp[j] = s;
            pkA[j] = pk;
            lmax = fmaxf(lmax, s);
        }
        float m = lmax;
#pragma unroll
        for (int off = 32; off; off >>= 1) m = fmaxf(m, __shfl_xor(m, off));
        if (lane == 0) redm[wv] = m;
        __syncthreads();
        m = fmaxf(fmaxf(redm[0], redm[1]), fmaxf(redm[2], redm[3]));

        // pass 2a: exponentiate, fold phiK, sum
        float lsum = 0.0f;
        for (int j = tid; j <= i; j += 256) {
            const float e = __expf(sp[j] - m);
            lsum += e;
            sp[j] = e * pkA[j];
        }
#pragma unroll
        for (int off = 32; off; off >>= 1) lsum += __shfl_xor(lsum, off);
        if (lane == 0) reds[wv] = lsum;
        __syncthreads();
        const float sden = reds[0] + reds[1] + reds[2] + reds[3];

        // pass 2b: PV, 4-way j-split
        const float* __restrict__ vb = vh + (size_t)(b * L_) * DM_ + h * DV_ + lane;
        float acc = 0.0f;
        for (int j = wv; j <= i; j += 4)
            acc = fmaf(sp[j], vb[(size_t)j * DM_], acc);
        pv[wv][lane] = acc;
        __syncthreads();
        if (wv == 0) {
            const float tot = pv[0][lane] + pv[1][lane] + pv[2][lane] + pv[3][lane];
            oh[(size_t)(b * L_ + i) * DM_ + h * DV_ + lane] = vi ? tot / sden : 0.0f;
        }
        __syncthreads();
    }
}

// ---------------------------------------------------------------------------
// out[row, n] = sum_k oh[row, k] * Wo[k, n] + q[row, n], 8 rows per block.
__global__ __launch_bounds__(256) void out8_kernel(const float* __restrict__ oh,
                                                   const float* __restrict__ Wo,
                                                   const float* __restrict__ q,
                                                   float* __restrict__ out) {
    __shared__ __align__(16) float xr[8][DM_];
    const int tid = threadIdx.x;
    const int row0 = blockIdx.x * 8;
    for (int x = tid; x < 8 * DM_; x += 256)
        xr[x >> 8][x & 255] = oh[(size_t)row0 * DM_ + x];
    __syncthreads();
    float acc[8] = {0, 0, 0, 0, 0, 0, 0, 0};
#pragma unroll 4
    for (int kk = 0; kk < DM_; ++kk) {
        const float w = Wo[(size_t)kk * DM_ + tid];
#pragma unroll
        for (int r = 0; r < 8; ++r) acc[r] = fmaf(xr[r][kk], w, acc[r]);
    }
#pragma unroll
    for (int r = 0; r < 8; ++r)
        out[(size_t)(row0 + r) * DM_ + tid] = acc[r] + q[(size_t)(row0 + r) * DM_ + tid];
}

// ---------------------------------------------------------------------------
extern "C" void kernel_launch(void* const* d_in, const int* in_sizes, int n_in,
                              void* d_out, int out_size, void* d_ws, size_t ws_size,
                              hipStream_t stream) {
    const float* q    = (const float*)d_in[0];
    const float* k    = (const float*)d_in[1];
    const float* v    = (const float*)d_in[2];
    const float* t_in = (const float*)d_in[3];
    const int*   c    = (const int*)d_in[4];
    // d_in[5] = mask: fixed causal triu, never read
    const float* ln_g = (const float*)d_in[6];
    const float* ln_b = (const float*)d_in[7];
    const float* Wq   = (const float*)d_in[8];
    const float* Wk   = (const float*)d_in[9];
    const float* Wv   = (const float*)d_in[10];
    const float* Wo   = (const float*)d_in[11];
    const float* W0   = (const float*)d_in[12];
    const float* b0   = (const float*)d_in[13];
    const float* W1   = (const float*)d_in[14];
    const float* b1   = (const float*)d_in[15];
    const float* Wf   = (const float*)d_in[16];
    const float* bf   = (const float*)d_in[17];
    float* outp = (float*)d_out;

    const size_t NROW = (size_t)B_ * L_;       // 1024
    const size_t SZ   = NROW * DM_;            // 262144 floats per buffer
    float* ws = (float*)d_ws;
    float* qh  = ws;
    float* kh  = ws + SZ;
    float* vh  = ws + 2 * SZ;
    float* oh  = ws + 3 * SZ;
    float* pkT = ws + 4 * SZ;                  // B*H*L*L = 2,097,152 floats (8 MB)

    qkv_kernel<<<dim3(384), dim3(256), 0, stream>>>(q, k, v, ln_g, ln_b,
                                                    Wq, Wk, Wv, qh, kh, vh);
    phik_kernel<<<dim3((size_t)B_ * (L_ / 2) * H_), dim3(256), 0, stream>>>(
        t_in, c, W0, b0, W1, b1, Wf, bf, pkT);
    attn_kernel<<<dim3((size_t)B_ * (L_ / 2) * H_), dim3(256), 0, stream>>>(
        qh, kh, vh, t_in, c, W0, b0, W1, b1, Wf, bf, pkT, oh);
    out8_kernel<<<dim3(NROW / 8), dim3(256), 0, stream>>>(oh, Wo, q, outp);
}

// Round 4
// 112.394 us; speedup vs baseline: 2.1573x; 1.3727x over previous
//
#include <hip/hip_runtime.h>
#include <math.h>

// Problem constants
#define B_  2
#define L_  512
#define DM_ 256
#define H_  4
#define DK_ 64
#define DV_ 64
#define T_  8
#define PW_ 8

// ---------------------------------------------------------------------------
// Fast exact-GELU: erf via Abramowitz-Stegun 7.1.26 (|err| <= 1.5e-7), branch-free.
__device__ __forceinline__ float gelu_fast(float x) {
    const float z  = x * 0.70710678118654752440f;
    const float az = fabsf(z);
    const float t  = __builtin_amdgcn_rcpf(fmaf(0.3275911f, az, 1.0f));
    float p = fmaf(t, 1.061405429f, -1.453152027f);
    p = fmaf(t, p, 1.421413741f);
    p = fmaf(t, p, -0.284496736f);
    p = fmaf(t, p, 0.254829592f);
    p *= t;
    const float e  = __expf(-az * az);
    float er = fmaf(-p, e, 1.0f);          // erf(|z|)
    er = copysignf(er, z);
    return 0.5f * x * (1.0f + er);
}

// phi MLP with wave-uniform type: 33 scalar params in registers, W1 via
// uniform-address (broadcast) LDS float4 reads.
__device__ __forceinline__ float phi_eval_u(
        const float* __restrict__ w0r, const float* __restrict__ b0r,
        const float4* __restrict__ W14, const float* __restrict__ b1r,
        const float* __restrict__ wfr, float bfv, float delta) {
    float h1[PW_];
#pragma unroll
    for (int w = 0; w < PW_; ++w)
        h1[w] = gelu_fast(fmaf(delta, w0r[w], b0r[w]));
    float out = bfv;
#pragma unroll
    for (int u = 0; u < PW_; ++u) {
        const float4 c0 = W14[u * 2];
        const float4 c1 = W14[u * 2 + 1];
        float a = b1r[u];
        a = fmaf(c0.x, h1[0], a); a = fmaf(c0.y, h1[1], a);
        a = fmaf(c0.z, h1[2], a); a = fmaf(c0.w, h1[3], a);
        a = fmaf(c1.x, h1[4], a); a = fmaf(c1.y, h1[5], a);
        a = fmaf(c1.z, h1[6], a); a = fmaf(c1.w, h1[7], a);
        out = fmaf(wfr[u], gelu_fast(a), out);
    }
    return out;
}

// ---------------------------------------------------------------------------
// Fused LN + 3 projections. seg 0: qh = LN(q)@Wq ; seg 1: kh = k@Wk ; seg 2: vh = v@Wv.
__global__ __launch_bounds__(256) void qkv_kernel(
        const float* __restrict__ q, const float* __restrict__ k,
        const float* __restrict__ v, const float* __restrict__ ln_g,
        const float* __restrict__ ln_b, const float* __restrict__ Wq,
        const float* __restrict__ Wk, const float* __restrict__ Wv,
        float* __restrict__ qh, float* __restrict__ kh, float* __restrict__ vh) {
    __shared__ __align__(16) float xr[8][DM_];
    const int tid = threadIdx.x;
    const int seg = blockIdx.x >> 7;
    const int row0 = (blockIdx.x & 127) * 8;
    const float* src = seg == 0 ? q : (seg == 1 ? k : v);
    const float* W   = seg == 0 ? Wq : (seg == 1 ? Wk : Wv);
    float* dst       = seg == 0 ? qh : (seg == 1 ? kh : vh);
    for (int x = tid; x < 8 * DM_; x += 256)
        xr[x >> 8][x & 255] = src[(size_t)row0 * DM_ + x];
    __syncthreads();
    if (seg == 0) {   // LayerNorm the 8 staged rows (4 waves x 2 rows)
        const int lane = tid & 63, wv = tid >> 6;
#pragma unroll
        for (int rr = 0; rr < 2; ++rr) {
            const int r = wv * 2 + rr;
            float x0 = xr[r][lane], x1 = xr[r][lane + 64];
            float x2 = xr[r][lane + 128], x3 = xr[r][lane + 192];
            float s = x0 + x1 + x2 + x3;
#pragma unroll
            for (int off = 32; off; off >>= 1) s += __shfl_xor(s, off);
            const float mean = s * (1.0f / 256.0f);
            x0 -= mean; x1 -= mean; x2 -= mean; x3 -= mean;
            float s2 = x0 * x0 + x1 * x1 + x2 * x2 + x3 * x3;
#pragma unroll
            for (int off = 32; off; off >>= 1) s2 += __shfl_xor(s2, off);
            const float rstd = rsqrtf(s2 * (1.0f / 256.0f) + 1e-6f);
            xr[r][lane]       = x0 * rstd * ln_g[lane]       + ln_b[lane];
            xr[r][lane + 64]  = x1 * rstd * ln_g[lane + 64]  + ln_b[lane + 64];
            xr[r][lane + 128] = x2 * rstd * ln_g[lane + 128] + ln_b[lane + 128];
            xr[r][lane + 192] = x3 * rstd * ln_g[lane + 192] + ln_b[lane + 192];
        }
        __syncthreads();
    }
    float acc[8] = {0, 0, 0, 0, 0, 0, 0, 0};
#pragma unroll 4
    for (int kk = 0; kk < DM_; ++kk) {
        const float w = W[(size_t)kk * DM_ + tid];
#pragma unroll
        for (int r = 0; r < 8; ++r) acc[r] = fmaf(xr[r][kk], w, acc[r]);
    }
#pragma unroll
    for (int r = 0; r < 8; ++r)
        dst[(size_t)(row0 + r) * DM_ + tid] = acc[r];
}

// ---------------------------------------------------------------------------
// phiK table: pkT[b][h][i][j] = phi_{c_j,h}(t_i - t_j) * (c_j < T).
// ONE WAVE PER COLUMN (b, j, h): type is wave-uniform -> params in SGPR/regs,
// no block barriers except the staging one. 4096 waves, fully resident.
__global__ __launch_bounds__(256) void phik_kernel(
        const float* __restrict__ t_in, const int* __restrict__ c,
        const float* __restrict__ W0, const float* __restrict__ b0,
        const float* __restrict__ W1, const float* __restrict__ b1,
        const float* __restrict__ Wf, const float* __restrict__ bfp,
        float* __restrict__ pkT) {
    __shared__ __align__(16) float W1s[4][64];
    const int tid = threadIdx.x, lane = tid & 63, wv = tid >> 6;
    const int g = blockIdx.x * 4 + wv;        // 0..4095
    const int j = g >> 3;                     // heavy column j=0 first
    const int bh = g & 7;
    const int b = bh >> 2, h = bh & 3;

    const float tj = t_in[b * L_ + j];
    const int cw = c[b * L_ + j];
    const bool vj = (cw < T_);
    const int ct = min(max(cw, 0), T_ - 1);
    const int base = __builtin_amdgcn_readfirstlane(ct * H_ + h);

    W1s[wv][lane] = W1[base * 64 + lane];
    float w0r[8], b0r[8], b1r[8], wfr[8];
#pragma unroll
    for (int w = 0; w < 8; ++w) {
        w0r[w] = W0[base * 8 + w];
        b0r[w] = b0[base * 8 + w];
        b1r[w] = b1[base * 8 + w];
        wfr[w] = Wf[base * 8 + w];
    }
    const float bfv = bfp[base];
    __syncthreads();
    const float4* W14 = reinterpret_cast<const float4*>(W1s[wv]);
    float* dst = pkT + ((size_t)(b * H_ + h) * L_) * L_ + j;
    if (vj) {
        for (int i = j + lane; i < L_; i += 64)
            dst[(size_t)i * L_] = phi_eval_u(w0r, b0r, W14, b1r, wfr, bfv,
                                             t_in[b * L_ + i] - tj);
    } else {
        for (int i = j + lane; i < L_; i += 64)
            dst[(size_t)i * L_] = 0.0f;
    }
}

// ---------------------------------------------------------------------------
// Attention: ONE WAVE PER ROW (b, i, h). phiQ inline (type wave-uniform),
// phiK from table (coalesced), reductions via shfl. All 4 waves of a block
// share the same i -> the two __syncthreads are perfectly balanced.
__global__ __launch_bounds__(256) void attn_kernel(
        const float* __restrict__ qh, const float* __restrict__ kh,
        const float* __restrict__ vh, const float* __restrict__ t_in,
        const int* __restrict__ c, const float* __restrict__ W0,
        const float* __restrict__ b0, const float* __restrict__ W1,
        const float* __restrict__ b1, const float* __restrict__ Wf,
        const float* __restrict__ bfp, const float* __restrict__ pkT,
        float* __restrict__ oh) {
    __shared__ __align__(16) float W1s[4][64];
    __shared__ __align__(16) float qs[4][DK_];
    __shared__ float sw[4][L_];
    __shared__ float pkw[4][L_];

    const int tid = threadIdx.x, lane = tid & 63, wv = tid >> 6;
    const int g = blockIdx.x * 4 + wv;        // 0..4095
    const int i = (L_ - 1) - (g >> 3);        // heavy rows first
    const int bh = g & 7;
    const int b = bh >> 2, h = bh & 3;
    const int row = b * L_ + i;

    const float ti = t_in[row];
    const int cw = c[row];
    const bool vi = (cw < T_);
    const int ct = min(max(cw, 0), T_ - 1);
    const int base = __builtin_amdgcn_readfirstlane(ct * H_ + h);

    W1s[wv][lane] = W1[base * 64 + lane];
    qs[wv][lane] = qh[(size_t)row * DM_ + h * DK_ + lane];
    float w0r[8], b0r[8], b1r[8], wfr[8];
#pragma unroll
    for (int w = 0; w < 8; ++w) {
        w0r[w] = W0[base * 8 + w];
        b0r[w] = b0[base * 8 + w];
        b1r[w] = b1[base * 8 + w];
        wfr[w] = Wf[base * 8 + w];
    }
    const float bfv = bfp[base];
    __syncthreads();

    const float4* W14 = reinterpret_cast<const float4*>(W1s[wv]);
    const float4* qs4 = reinterpret_cast<const float4*>(qs[wv]);
    const float* pkrow = pkT + ((size_t)(b * H_ + h) * L_ + i) * L_;
    const float* kbase = kh + (size_t)(b * L_) * DM_ + h * DK_;
    const float* tbase = t_in + b * L_;

    // ---- pass 1: scores, per-lane max (lane-strided j) --------------------
    float lmax = -INFINITY;
    for (int j = lane; j <= i; j += 64) {
        const float pk = pkrow[j];
        const float pq = vi ? phi_eval_u(w0r, b0r, W14, b1r, wfr, bfv, ti - tbase[j])
                            : 0.0f;
        const float4* kr4 = reinterpret_cast<const float4*>(kbase + (size_t)j * DM_);
        float dot = 0.0f;
#pragma unroll
        for (int d4 = 0; d4 < DK_ / 4; ++d4) {
            const float4 a = qs4[d4];
            const float4 kk = kr4[d4];
            dot = fmaf(a.x, kk.x, fmaf(a.y, kk.y, fmaf(a.z, kk.z, fmaf(a.w, kk.w, dot))));
        }
        const float s = dot * pq * pk * 0.125f;   // / sqrt(64)
        sw[wv][j] = s;
        pkw[wv][j] = pk;
        lmax = fmaxf(lmax, s);
    }
    float m = lmax;
#pragma unroll
    for (int off = 32; off; off >>= 1) m = fmaxf(m, __shfl_xor(m, off));

    // ---- pass 2a: exponentiate, fold phiK, sum (own-lane j's, no race) ----
    float lsum = 0.0f;
    for (int j = lane; j <= i; j += 64) {
        const float e = __expf(sw[wv][j] - m);
        lsum += e;
        sw[wv][j] = e * pkw[wv][j];
    }
#pragma unroll
    for (int off = 32; off; off >>= 1) lsum += __shfl_xor(lsum, off);
    const float sden = lsum;
    __syncthreads();   // cross-lane LDS visibility for PV (waves balanced)

    // ---- PV: lane = d, broadcast weights, coalesced v ---------------------
    const float* __restrict__ vb = vh + (size_t)(b * L_) * DM_ + h * DV_ + lane;
    float acc = 0.0f;
#pragma unroll 4
    for (int j = 0; j <= i; ++j)
        acc = fmaf(sw[wv][j], vb[(size_t)j * DM_], acc);
    oh[(size_t)row * DM_ + h * DV_ + lane] = vi ? acc / sden : 0.0f;
}

// ---------------------------------------------------------------------------
// out[row, n] = sum_k oh[row, k] * Wo[k, n] + q[row, n], 8 rows per block.
__global__ __launch_bounds__(256) void out8_kernel(const float* __restrict__ oh,
                                                   const float* __restrict__ Wo,
                                                   const float* __restrict__ q,
                                                   float* __restrict__ out) {
    __shared__ __align__(16) float xr[8][DM_];
    const int tid = threadIdx.x;
    const int row0 = blockIdx.x * 8;
    for (int x = tid; x < 8 * DM_; x += 256)
        xr[x >> 8][x & 255] = oh[(size_t)row0 * DM_ + x];
    __syncthreads();
    float acc[8] = {0, 0, 0, 0, 0, 0, 0, 0};
#pragma unroll 4
    for (int kk = 0; kk < DM_; ++kk) {
        const float w = Wo[(size_t)kk * DM_ + tid];
#pragma unroll
        for (int r = 0; r < 8; ++r) acc[r] = fmaf(xr[r][kk], w, acc[r]);
    }
#pragma unroll
    for (int r = 0; r < 8; ++r)
        out[(size_t)(row0 + r) * DM_ + tid] = acc[r] + q[(size_t)(row0 + r) * DM_ + tid];
}

// ---------------------------------------------------------------------------
extern "C" void kernel_launch(void* const* d_in, const int* in_sizes, int n_in,
                              void* d_out, int out_size, void* d_ws, size_t ws_size,
                              hipStream_t stream) {
    const float* q    = (const float*)d_in[0];
    const float* k    = (const float*)d_in[1];
    const float* v    = (const float*)d_in[2];
    const float* t_in = (const float*)d_in[3];
    const int*   c    = (const int*)d_in[4];
    // d_in[5] = mask: fixed causal triu, never read
    const float* ln_g = (const float*)d_in[6];
    const float* ln_b = (const float*)d_in[7];
    const float* Wq   = (const float*)d_in[8];
    const float* Wk   = (const float*)d_in[9];
    const float* Wv   = (const float*)d_in[10];
    const float* Wo   = (const float*)d_in[11];
    const float* W0   = (const float*)d_in[12];
    const float* b0   = (const float*)d_in[13];
    const float* W1   = (const float*)d_in[14];
    const float* b1   = (const float*)d_in[15];
    const float* Wf   = (const float*)d_in[16];
    const float* bf   = (const float*)d_in[17];
    float* outp = (float*)d_out;

    const size_t NROW = (size_t)B_ * L_;       // 1024
    const size_t SZ   = NROW * DM_;            // 262144 floats per buffer
    float* ws = (float*)d_ws;
    float* qh  = ws;
    float* kh  = ws + SZ;
    float* vh  = ws + 2 * SZ;
    float* oh  = ws + 3 * SZ;
    float* pkT = ws + 4 * SZ;                  // B*H*L*L = 2,097,152 floats (8 MB)

    qkv_kernel<<<dim3(384), dim3(256), 0, stream>>>(q, k, v, ln_g, ln_b,
                                                    Wq, Wk, Wv, qh, kh, vh);
    phik_kernel<<<dim3(1024), dim3(256), 0, stream>>>(
        t_in, c, W0, b0, W1, b1, Wf, bf, pkT);
    attn_kernel<<<dim3(1024), dim3(256), 0, stream>>>(
        qh, kh, vh, t_in, c, W0, b0, W1, b1, Wf, bf, pkT, oh);
    out8_kernel<<<dim3(NROW / 8), dim3(256), 0, stream>>>(oh, Wo, q, outp);
}

// Round 5
// 104.370 us; speedup vs baseline: 2.3231x; 1.0769x over previous
//
#include <hip/hip_runtime.h>
#include <math.h>

// Problem constants
#define B_  2
#define L_  512
#define DM_ 256
#define H_  4
#define DK_ 64
#define DV_ 64
#define T_  8
#define PW_ 8

// ---------------------------------------------------------------------------
// Fast exact-GELU: erf via Abramowitz-Stegun 7.1.26 (|err| <= 1.5e-7), branch-free.
__device__ __forceinline__ float gelu_fast(float x) {
    const float z  = x * 0.70710678118654752440f;
    const float az = fabsf(z);
    const float t  = __builtin_amdgcn_rcpf(fmaf(0.3275911f, az, 1.0f));
    float p = fmaf(t, 1.061405429f, -1.453152027f);
    p = fmaf(t, p, 1.421413741f);
    p = fmaf(t, p, -0.284496736f);
    p = fmaf(t, p, 0.254829592f);
    p *= t;
    const float e  = __expf(-az * az);
    float er = fmaf(-p, e, 1.0f);          // erf(|z|)
    er = copysignf(er, z);
    return 0.5f * x * (1.0f + er);
}

// phi MLP with wave-uniform type: 33 scalar params in registers, W1 via
// uniform-address (broadcast) LDS float4 reads.
__device__ __forceinline__ float phi_eval_u(
        const float* __restrict__ w0r, const float* __restrict__ b0r,
        const float4* __restrict__ W14, const float* __restrict__ b1r,
        const float* __restrict__ wfr, float bfv, float delta) {
    float h1[PW_];
#pragma unroll
    for (int w = 0; w < PW_; ++w)
        h1[w] = gelu_fast(fmaf(delta, w0r[w], b0r[w]));
    float out = bfv;
#pragma unroll
    for (int u = 0; u < PW_; ++u) {
        const float4 c0 = W14[u * 2];
        const float4 c1 = W14[u * 2 + 1];
        float a = b1r[u];
        a = fmaf(c0.x, h1[0], a); a = fmaf(c0.y, h1[1], a);
        a = fmaf(c0.z, h1[2], a); a = fmaf(c0.w, h1[3], a);
        a = fmaf(c1.x, h1[4], a); a = fmaf(c1.y, h1[5], a);
        a = fmaf(c1.z, h1[6], a); a = fmaf(c1.w, h1[7], a);
        out = fmaf(wfr[u], gelu_fast(a), out);
    }
    return out;
}

// ---------------------------------------------------------------------------
// Fused LN + 3 projections. seg 0: qh = LN(q)@Wq ; seg 1: khT = k@Wk (transposed
// interleaved layout [b][h][d4][j][4]) ; seg 2: vh = v@Wv.
__global__ __launch_bounds__(256) void qkv_kernel(
        const float* __restrict__ q, const float* __restrict__ k,
        const float* __restrict__ v, const float* __restrict__ ln_g,
        const float* __restrict__ ln_b, const float* __restrict__ Wq,
        const float* __restrict__ Wk, const float* __restrict__ Wv,
        float* __restrict__ qh, float* __restrict__ khT, float* __restrict__ vh) {
    __shared__ __align__(16) float xr[8][DM_];
    const int tid = threadIdx.x;
    const int seg = blockIdx.x >> 7;
    const int row0 = (blockIdx.x & 127) * 8;
    const float* src = seg == 0 ? q : (seg == 1 ? k : v);
    const float* W   = seg == 0 ? Wq : (seg == 1 ? Wk : Wv);
    for (int x = tid; x < 8 * DM_; x += 256)
        xr[x >> 8][x & 255] = src[(size_t)row0 * DM_ + x];
    __syncthreads();
    if (seg == 0) {   // LayerNorm the 8 staged rows (4 waves x 2 rows)
        const int lane = tid & 63, wv = tid >> 6;
#pragma unroll
        for (int rr = 0; rr < 2; ++rr) {
            const int r = wv * 2 + rr;
            float x0 = xr[r][lane], x1 = xr[r][lane + 64];
            float x2 = xr[r][lane + 128], x3 = xr[r][lane + 192];
            float s = x0 + x1 + x2 + x3;
#pragma unroll
            for (int off = 32; off; off >>= 1) s += __shfl_xor(s, off);
            const float mean = s * (1.0f / 256.0f);
            x0 -= mean; x1 -= mean; x2 -= mean; x3 -= mean;
            float s2 = x0 * x0 + x1 * x1 + x2 * x2 + x3 * x3;
#pragma unroll
            for (int off = 32; off; off >>= 1) s2 += __shfl_xor(s2, off);
            const float rstd = rsqrtf(s2 * (1.0f / 256.0f) + 1e-6f);
            xr[r][lane]       = x0 * rstd * ln_g[lane]       + ln_b[lane];
            xr[r][lane + 64]  = x1 * rstd * ln_g[lane + 64]  + ln_b[lane + 64];
            xr[r][lane + 128] = x2 * rstd * ln_g[lane + 128] + ln_b[lane + 128];
            xr[r][lane + 192] = x3 * rstd * ln_g[lane + 192] + ln_b[lane + 192];
        }
        __syncthreads();
    }
    float acc[8] = {0, 0, 0, 0, 0, 0, 0, 0};
#pragma unroll 4
    for (int kk = 0; kk < DM_; ++kk) {
        const float w = W[(size_t)kk * DM_ + tid];
#pragma unroll
        for (int r = 0; r < 8; ++r) acc[r] = fmaf(xr[r][kk], w, acc[r]);
    }
    if (seg == 1) {
        // khT[((b*H+h)*16 + d4) * (L*4) + j*4 + e]
        const int h = tid >> 6, d = tid & 63, d4 = d >> 2, e = d & 3;
        const int b = row0 >> 9;
        const int lrow0 = row0 & (L_ - 1);
        float* base = khT + ((size_t)(b * H_ + h) * 16 + d4) * (L_ * 4) + e;
#pragma unroll
        for (int r = 0; r < 8; ++r)
            base[(size_t)(lrow0 + r) * 4] = acc[r];
    } else {
        float* dst = seg == 0 ? qh : vh;
#pragma unroll
        for (int r = 0; r < 8; ++r)
            dst[(size_t)(row0 + r) * DM_ + tid] = acc[r];
    }
}

// ---------------------------------------------------------------------------
// phiK table: pkT[b][h][i][j] = phi_{c_j,h}(t_i - t_j) * (c_j < T).
// ONE WAVE PER BLOCK, one (b, column, h) per wave; heavy columns first.
__global__ __launch_bounds__(64) void phik_kernel(
        const float* __restrict__ t_in, const int* __restrict__ c,
        const float* __restrict__ W0, const float* __restrict__ b0,
        const float* __restrict__ W1, const float* __restrict__ b1,
        const float* __restrict__ Wf, const float* __restrict__ bfp,
        float* __restrict__ pkT) {
    __shared__ __align__(16) float W1s[64];
    const int lane = threadIdx.x;
    const int g = blockIdx.x;                 // 0..4095
    const int j = g >> 3;                     // heavy column j=0 first
    const int bh = g & 7;
    const int b = bh >> 2, h = bh & 3;

    const float tj = t_in[b * L_ + j];
    const int cw = c[b * L_ + j];
    const bool vj = (cw < T_);
    const int ct = min(max(cw, 0), T_ - 1);
    const int base = __builtin_amdgcn_readfirstlane(ct * H_ + h);

    W1s[lane] = W1[base * 64 + lane];
    float w0r[8], b0r[8], b1r[8], wfr[8];
#pragma unroll
    for (int w = 0; w < 8; ++w) {
        w0r[w] = W0[base * 8 + w];
        b0r[w] = b0[base * 8 + w];
        b1r[w] = b1[base * 8 + w];
        wfr[w] = Wf[base * 8 + w];
    }
    const float bfv = bfp[base];
    __syncthreads();
    const float4* W14 = reinterpret_cast<const float4*>(W1s);
    float* dst = pkT + ((size_t)(b * H_ + h) * L_) * L_ + j;
    if (vj) {
        for (int i = j + lane; i < L_; i += 64)
            dst[(size_t)i * L_] = phi_eval_u(w0r, b0r, W14, b1r, wfr, bfv,
                                             t_in[b * L_ + i] - tj);
    } else {
        for (int i = j + lane; i < L_; i += 64)
            dst[(size_t)i * L_] = 0.0f;
    }
}

// ---------------------------------------------------------------------------
// Attention: ONE WAVE PER BLOCK, one (b, row, h) per wave; heavy rows first.
// phiQ inline (type wave-uniform), phiK from table (coalesced), K from
// transposed-interleaved khT (fully coalesced float4 loads).
__global__ __launch_bounds__(64) void attn_kernel(
        const float* __restrict__ qh, const float* __restrict__ khT,
        const float* __restrict__ vh, const float* __restrict__ t_in,
        const int* __restrict__ c, const float* __restrict__ W0,
        const float* __restrict__ b0, const float* __restrict__ W1,
        const float* __restrict__ b1, const float* __restrict__ Wf,
        const float* __restrict__ bfp, const float* __restrict__ pkT,
        float* __restrict__ oh) {
    __shared__ __align__(16) float W1s[64];
    __shared__ __align__(16) float qs[DK_];
    __shared__ float sw[L_];
    __shared__ float pkw[L_];

    const int lane = threadIdx.x;
    const int g = blockIdx.x;                 // 0..4095
    const int i = (L_ - 1) - (g >> 3);        // heavy rows first
    const int bh = g & 7;
    const int b = bh >> 2, h = bh & 3;
    const int row = b * L_ + i;

    const float ti = t_in[row];
    const int cw = c[row];
    const bool vi = (cw < T_);
    const int ct = min(max(cw, 0), T_ - 1);
    const int base = __builtin_amdgcn_readfirstlane(ct * H_ + h);

    W1s[lane] = W1[base * 64 + lane];
    qs[lane] = qh[(size_t)row * DM_ + h * DK_ + lane];
    float w0r[8], b0r[8], b1r[8], wfr[8];
#pragma unroll
    for (int w = 0; w < 8; ++w) {
        w0r[w] = W0[base * 8 + w];
        b0r[w] = b0[base * 8 + w];
        b1r[w] = b1[base * 8 + w];
        wfr[w] = Wf[base * 8 + w];
    }
    const float bfv = bfp[base];
    __syncthreads();

    const float4* W14 = reinterpret_cast<const float4*>(W1s);
    const float4* qs4 = reinterpret_cast<const float4*>(qs);
    const float* pkrow = pkT + ((size_t)(b * H_ + h) * L_ + i) * L_;
    const float4* kT4 = reinterpret_cast<const float4*>(
        khT + (size_t)(b * H_ + h) * 16 * (L_ * 4));
    const float* tbase = t_in + b * L_;

    // ---- pass 1: scores, per-lane max (lane-strided j) --------------------
    float lmax = -INFINITY;
    for (int j = lane; j <= i; j += 64) {
        const float pk = pkrow[j];
        const float pq = vi ? phi_eval_u(w0r, b0r, W14, b1r, wfr, bfv, ti - tbase[j])
                            : 0.0f;
        float dot = 0.0f;
#pragma unroll
        for (int d4 = 0; d4 < DK_ / 4; ++d4) {
            const float4 kk = kT4[(size_t)d4 * L_ + j];   // coalesced across lanes
            const float4 a = qs4[d4];                     // uniform LDS broadcast
            dot = fmaf(a.x, kk.x, fmaf(a.y, kk.y, fmaf(a.z, kk.z, fmaf(a.w, kk.w, dot))));
        }
        const float s = dot * pq * pk * 0.125f;   // / sqrt(64)
        sw[j] = s;
        pkw[j] = pk;
        lmax = fmaxf(lmax, s);
    }
    float m = lmax;
#pragma unroll
    for (int off = 32; off; off >>= 1) m = fmaxf(m, __shfl_xor(m, off));

    // ---- pass 2a: exponentiate, fold phiK, sum (own-lane j's) -------------
    float lsum = 0.0f;
    for (int j = lane; j <= i; j += 64) {
        const float e = __expf(sw[j] - m);
        lsum += e;
        sw[j] = e * pkw[j];
    }
#pragma unroll
    for (int off = 32; off; off >>= 1) lsum += __shfl_xor(lsum, off);
    const float sden = lsum;
    __syncthreads();   // cross-lane LDS visibility for PV (single wave: cheap)

    // ---- PV: lane = d, broadcast weights, coalesced v, 4 accumulators -----
    const float* __restrict__ vb = vh + (size_t)(b * L_) * DM_ + h * DV_ + lane;
    float a0 = 0.0f, a1 = 0.0f, a2 = 0.0f, a3 = 0.0f;
    int j = 0;
    for (; j + 3 <= i; j += 4) {
        a0 = fmaf(sw[j],     vb[(size_t)j * DM_],       a0);
        a1 = fmaf(sw[j + 1], vb[(size_t)(j + 1) * DM_], a1);
        a2 = fmaf(sw[j + 2], vb[(size_t)(j + 2) * DM_], a2);
        a3 = fmaf(sw[j + 3], vb[(size_t)(j + 3) * DM_], a3);
    }
    for (; j <= i; ++j)
        a0 = fmaf(sw[j], vb[(size_t)j * DM_], a0);
    const float acc = (a0 + a1) + (a2 + a3);
    oh[(size_t)row * DM_ + h * DV_ + lane] = vi ? acc / sden : 0.0f;
}

// ---------------------------------------------------------------------------
// out[row, n] = sum_k oh[row, k] * Wo[k, n] + q[row, n], 8 rows per block.
__global__ __launch_bounds__(256) void out8_kernel(const float* __restrict__ oh,
                                                   const float* __restrict__ Wo,
                                                   const float* __restrict__ q,
                                                   float* __restrict__ out) {
    __shared__ __align__(16) float xr[8][DM_];
    const int tid = threadIdx.x;
    const int row0 = blockIdx.x * 8;
    for (int x = tid; x < 8 * DM_; x += 256)
        xr[x >> 8][x & 255] = oh[(size_t)row0 * DM_ + x];
    __syncthreads();
    float acc[8] = {0, 0, 0, 0, 0, 0, 0, 0};
#pragma unroll 4
    for (int kk = 0; kk < DM_; ++kk) {
        const float w = Wo[(size_t)kk * DM_ + tid];
#pragma unroll
        for (int r = 0; r < 8; ++r) acc[r] = fmaf(xr[r][kk], w, acc[r]);
    }
#pragma unroll
    for (int r = 0; r < 8; ++r)
        out[(size_t)(row0 + r) * DM_ + tid] = acc[r] + q[(size_t)(row0 + r) * DM_ + tid];
}

// ---------------------------------------------------------------------------
extern "C" void kernel_launch(void* const* d_in, const int* in_sizes, int n_in,
                              void* d_out, int out_size, void* d_ws, size_t ws_size,
                              hipStream_t stream) {
    const float* q    = (const float*)d_in[0];
    const float* k    = (const float*)d_in[1];
    const float* v    = (const float*)d_in[2];
    const float* t_in = (const float*)d_in[3];
    const int*   c    = (const int*)d_in[4];
    // d_in[5] = mask: fixed causal triu, never read
    const float* ln_g = (const float*)d_in[6];
    const float* ln_b = (const float*)d_in[7];
    const float* Wq   = (const float*)d_in[8];
    const float* Wk   = (const float*)d_in[9];
    const float* Wv   = (const float*)d_in[10];
    const float* Wo   = (const float*)d_in[11];
    const float* W0   = (const float*)d_in[12];
    const float* b0   = (const float*)d_in[13];
    const float* W1   = (const float*)d_in[14];
    const float* b1   = (const float*)d_in[15];
    const float* Wf   = (const float*)d_in[16];
    const float* bf   = (const float*)d_in[17];
    float* outp = (float*)d_out;

    const size_t NROW = (size_t)B_ * L_;       // 1024
    const size_t SZ   = NROW * DM_;            // 262144 floats per buffer
    float* ws = (float*)d_ws;
    float* qh  = ws;
    float* khT = ws + SZ;                      // B*H*16*L*4 = 262144 floats
    float* vh  = ws + 2 * SZ;
    float* oh  = ws + 3 * SZ;
    float* pkT = ws + 4 * SZ;                  // B*H*L*L = 2,097,152 floats (8 MB)

    qkv_kernel<<<dim3(384), dim3(256), 0, stream>>>(q, k, v, ln_g, ln_b,
                                                    Wq, Wk, Wv, qh, khT, vh);
    phik_kernel<<<dim3(4096), dim3(64), 0, stream>>>(
        t_in, c, W0, b0, W1, b1, Wf, bf, pkT);
    attn_kernel<<<dim3(4096), dim3(64), 0, stream>>>(
        qh, khT, vh, t_in, c, W0, b0, W1, b1, Wf, bf, pkT, oh);
    out8_kernel<<<dim3(NROW / 8), dim3(256), 0, stream>>>(oh, Wo, q, outp);
}